// Round 8
// baseline (864.064 us; speedup 1.0000x reference)
//
#include <hip/hip_runtime.h>
#include <math.h>

#define NB   2048   // batch
#define NSEQ 65     // sequence incl. origin
#define ND   256    // IN_DIM (K)
#define NH   8      // heads
#define NL   256    // L
#define NS   64     // walk length (S-1)
#define APAD 264    // padded A row (fp16 elems)

typedef _Float16 f16;
typedef _Float16 f16x4 __attribute__((ext_vector_type(4)));
typedef _Float16 f16x8 __attribute__((ext_vector_type(8)));
typedef float    f32x4 __attribute__((ext_vector_type(4)));

__device__ __forceinline__ float sigmoidf_(float x) {
    return __builtin_amdgcn_rcpf(1.0f + __expf(-x));
}

// ---------------------------------------------------------------------------
// Prep: Wq/Wv/Wk (H,K,N) f32 -> wh[(h*3+m)][n][k] f16 (k contiguous), m=q,v,k
// ---------------------------------------------------------------------------
__global__ __launch_bounds__(256) void wh_kernel(const float* __restrict__ Wq,
                                                 const float* __restrict__ Wv,
                                                 const float* __restrict__ Wk,
                                                 f16* __restrict__ wh) {
    int hm = blockIdx.x >> 4;            // h*3+m, 24 values
    int h  = hm / 3, m = hm % 3;
    int n  = ((blockIdx.x & 15) << 4) + (threadIdx.x >> 4);
    int kc = (threadIdx.x & 15) << 4;
    const float* src = (m == 0 ? Wq : (m == 1 ? Wv : Wk)) + h * (ND * NL);
    f16x8 t0, t1;
    #pragma unroll
    for (int j = 0; j < 8; ++j) t0[j] = (f16)src[(kc + j) * NL + n];
    #pragma unroll
    for (int j = 0; j < 8; ++j) t1[j] = (f16)src[(kc + 8 + j) * NL + n];
    f16* dst = wh + ((size_t)(hm * 256 + n)) * 256 + kc;
    *(f16x8*)dst       = t0;
    *(f16x8*)(dst + 8) = t1;
}

// ---------------------------------------------------------------------------
// Prep: O (2048,256) f32 -> OT[n][k] f16 (k contiguous)
// ---------------------------------------------------------------------------
__global__ __launch_bounds__(256) void ot_kernel(const float* __restrict__ O,
                                                 f16* __restrict__ OT) {
    int n = blockIdx.x;
    int t = threadIdx.x;
    f16x8 v;
    #pragma unroll
    for (int j = 0; j < 8; ++j) v[j] = (f16)O[(size_t)(t * 8 + j) * 256 + n];
    *(f16x8*)(OT + (size_t)n * 2048 + t * 8) = v;
}

// ---------------------------------------------------------------------------
// PKT[h][l][s] = P[s]·Wk[h][:,l]  (transposed: epilogue reads float4 over s)
// ---------------------------------------------------------------------------
__global__ __launch_bounds__(256) void pkt_kernel(const float* __restrict__ P,
                                                  const float* __restrict__ Wk,
                                                  float* __restrict__ PKT) {
    int h = blockIdx.x >> 6;
    int s = blockIdx.x & 63;
    int t = threadIdx.x;
    __shared__ float p_s[ND];
    p_s[t] = P[s * ND + t];
    __syncthreads();
    const float* wk = Wk + h * (ND * NL) + t;
    float acc = 0.f;
    #pragma unroll 8
    for (int d = 0; d < ND; ++d) acc = fmaf(p_s[d], wk[d * NL], acc);
    PKT[((size_t)h * NL + t) * NS + s] = acc;
}

// ---------------------------------------------------------------------------
// OK[h][b][l] = origin_b · Wk[h][:,l]  as f16 MFMA GEMM
// ---------------------------------------------------------------------------
__global__ __launch_bounds__(256) void ok_gemm(const float* __restrict__ x,
                                               const f16*   __restrict__ wh,
                                               float* __restrict__ OK) {
    int mblk = blockIdx.x >> 4;          // 32
    int nblk = blockIdx.x & 15;          // 16
    int b0 = mblk * 64;
    int h  = nblk >> 1;
    int l0 = (nblk & 1) * 128;
    int t = threadIdx.x;
    int w = t >> 6, lane = t & 63, c = lane & 15, g = lane >> 4;

    __shared__ f16 Ao[64 * APAD];
    #pragma unroll
    for (int it = 0; it < 16; ++it) {
        int idx4 = it * 256 + t;
        int s = idx4 >> 6, kq = idx4 & 63;
        float4 v = *(const float4*)(x + (size_t)(b0 + s) * (NSEQ * ND) + kq * 4);
        *(f16x4*)(&Ao[s * APAD + kq * 4]) = (f16x4){(f16)v.x, (f16)v.y, (f16)v.z, (f16)v.w};
    }
    __syncthreads();

    f32x4 acc[4][2];
    #pragma unroll
    for (int mt = 0; mt < 4; ++mt)
        #pragma unroll
        for (int nt = 0; nt < 2; ++nt) acc[mt][nt] = (f32x4){0.f, 0.f, 0.f, 0.f};

    const f16* bb = wh + ((size_t)((h * 3 + 2) * 256 + l0 + w * 32 + c)) * 256;
    #pragma unroll 2
    for (int kk = 0; kk < 8; ++kk) {
        int k0 = kk * 32 + g * 8;
        f16x8 af[4];
        #pragma unroll
        for (int mt = 0; mt < 4; ++mt)
            af[mt] = *(const f16x8*)(&Ao[(mt * 16 + c) * APAD + k0]);
        #pragma unroll
        for (int nt = 0; nt < 2; ++nt) {
            f16x8 bf = *(const f16x8*)(bb + nt * 16 * 256 + k0);
            #pragma unroll
            for (int mt = 0; mt < 4; ++mt)
                acc[mt][nt] = __builtin_amdgcn_mfma_f32_16x16x32_f16(af[mt], bf, acc[mt][nt], 0, 0, 0);
        }
    }
    #pragma unroll
    for (int mt = 0; mt < 4; ++mt)
        #pragma unroll
        for (int nt = 0; nt < 2; ++nt)
            #pragma unroll
            for (int r = 0; r < 4; ++r)
                OK[((size_t)h * NB + b0 + mt * 16 + g * 4 + r) * NL + l0 + w * 32 + nt * 16 + c]
                    = acc[mt][nt][r];
}

// ---------------------------------------------------------------------------
// Main fused kernel: one block per batch; WAVE-PRIVATE HEADS (wave w owns
// heads 2w, 2w+1). Per head: 4 l-chunks of q-GEMM+edge (score partials in
// regs) -> in-wave softmax -> 4 l-chunks of v-GEMM+weighted sum -> res.
// ZERO per-head barriers; only the A-staging barrier. Bias dropped: softmax
// is invariant to the constant bias*sum(W) shift.
// ---------------------------------------------------------------------------
__global__ __launch_bounds__(256, 3) void attn_mfma(
        const float* __restrict__ x,
        const f16*   __restrict__ wh,
        const float* __restrict__ W,
        const float* __restrict__ PKT,
        const float* __restrict__ OK,
        f16* __restrict__ res) {
    int b = blockIdx.x;
    int t = threadIdx.x;
    int w    = t >> 6;
    int lane = t & 63;
    int c = lane & 15;
    int g = lane >> 4;

    __shared__ f16 A[NS * APAD];         // 33792 B walk tile (shared by all)

    const float* xb = x + (size_t)b * (NSEQ * ND);

    // --- stage A (walk) once ----------------------------------------------
    #pragma unroll
    for (int it = 0; it < 16; ++it) {
        int idx4 = it * 256 + t;
        int s  = idx4 >> 6;
        int kq = idx4 & 63;
        float4 v = *(const float4*)(xb + (1 + s) * ND + kq * 4);
        *(f16x4*)(&A[s * APAD + kq * 4]) = (f16x4){(f16)v.x, (f16)v.y, (f16)v.z, (f16)v.w};
    }
    __syncthreads();

    #pragma unroll
    for (int hh = 0; hh < 2; ++hh) {
        int h = w * 2 + hh;

        // ---- pass 1: q-GEMM + edge, l chunked 4x64; score partials in regs
        float part[4][4];                // [mt][r] -> s = mt*16 + g*4 + r
        #pragma unroll
        for (int mt = 0; mt < 4; ++mt)
            #pragma unroll
            for (int r = 0; r < 4; ++r) part[mt][r] = 0.f;

        for (int ch = 0; ch < 4; ++ch) {
            f32x4 acc[4][4];
            #pragma unroll
            for (int mt = 0; mt < 4; ++mt)
                #pragma unroll
                for (int nt = 0; nt < 4; ++nt) acc[mt][nt] = (f32x4){0.f, 0.f, 0.f, 0.f};

            const f16* bq = wh + ((size_t)((h * 3 + 0) * 256 + ch * 64 + c)) * 256;
            #pragma unroll 2
            for (int kk = 0; kk < 8; ++kk) {
                int k0 = kk * 32 + g * 8;
                f16x8 af[4];
                #pragma unroll
                for (int mt = 0; mt < 4; ++mt)
                    af[mt] = *(const f16x8*)(&A[(mt * 16 + c) * APAD + k0]);
                #pragma unroll
                for (int nt = 0; nt < 4; ++nt) {
                    f16x8 bf = *(const f16x8*)(bq + nt * 16 * 256 + k0);
                    #pragma unroll
                    for (int mt = 0; mt < 4; ++mt)
                        acc[mt][nt] = __builtin_amdgcn_mfma_f32_16x16x32_f16(af[mt], bf, acc[mt][nt], 0, 0, 0);
                }
            }
            // edge for this chunk (bias omitted: softmax-invariant)
            #pragma unroll
            for (int nt = 0; nt < 4; ++nt) {
                int l = ch * 64 + nt * 16 + c;
                float wl  = W[h * NL + l];
                float okv = OK[((size_t)h * NB + b) * NL + l];
                const float* pkcol = PKT + ((size_t)h * NL + l) * NS + g * 4;
                #pragma unroll
                for (int mt = 0; mt < 4; ++mt) {
                    float4 pk4 = *(const float4*)(pkcol + mt * 16);
                    float pks[4] = {pk4.x, pk4.y, pk4.z, pk4.w};
                    #pragma unroll
                    for (int r = 0; r < 4; ++r) {
                        float qs = sigmoidf_(acc[mt][nt][r]);
                        float ks = sigmoidf_(okv + pks[r]);
                        part[mt][r] = fmaf(__cosf(ks * qs), wl, part[mt][r]);
                    }
                }
            }
        }

        // ---- in-wave score reduction over c, then softmax over 64 s ------
        #pragma unroll
        for (int mt = 0; mt < 4; ++mt)
            #pragma unroll
            for (int r = 0; r < 4; ++r) {
                float v = part[mt][r];
                v += __shfl_xor(v, 1, 64);
                v += __shfl_xor(v, 2, 64);
                v += __shfl_xor(v, 4, 64);
                v += __shfl_xor(v, 8, 64);
                part[mt][r] = v;         // score[s], uniform over c
            }
        float m = part[0][0];
        #pragma unroll
        for (int mt = 0; mt < 4; ++mt)
            #pragma unroll
            for (int r = 0; r < 4; ++r) m = fmaxf(m, part[mt][r]);
        m = fmaxf(m, __shfl_xor(m, 16, 64));
        m = fmaxf(m, __shfl_xor(m, 32, 64));
        float ssum = 0.f;
        #pragma unroll
        for (int mt = 0; mt < 4; ++mt)
            #pragma unroll
            for (int r = 0; r < 4; ++r) {
                float e = __expf(part[mt][r] - m);
                part[mt][r] = e;
                ssum += e;
            }
        ssum += __shfl_xor(ssum, 16, 64);
        ssum += __shfl_xor(ssum, 32, 64);
        float rinv = __builtin_amdgcn_rcpf(ssum);
        #pragma unroll
        for (int mt = 0; mt < 4; ++mt)
            #pragma unroll
            for (int r = 0; r < 4; ++r) part[mt][r] *= rinv;   // p_s

        // ---- pass 2: v-GEMM + weighted sigmoid sum, l chunked 4x64 -------
        for (int ch = 0; ch < 4; ++ch) {
            f32x4 acc[4][4];
            #pragma unroll
            for (int mt = 0; mt < 4; ++mt)
                #pragma unroll
                for (int nt = 0; nt < 4; ++nt) acc[mt][nt] = (f32x4){0.f, 0.f, 0.f, 0.f};

            const f16* bv = wh + ((size_t)((h * 3 + 1) * 256 + ch * 64 + c)) * 256;
            #pragma unroll 2
            for (int kk = 0; kk < 8; ++kk) {
                int k0 = kk * 32 + g * 8;
                f16x8 af[4];
                #pragma unroll
                for (int mt = 0; mt < 4; ++mt)
                    af[mt] = *(const f16x8*)(&A[(mt * 16 + c) * APAD + k0]);
                #pragma unroll
                for (int nt = 0; nt < 4; ++nt) {
                    f16x8 bf = *(const f16x8*)(bv + nt * 16 * 256 + k0);
                    #pragma unroll
                    for (int mt = 0; mt < 4; ++mt)
                        acc[mt][nt] = __builtin_amdgcn_mfma_f32_16x16x32_f16(af[mt], bf, acc[mt][nt], 0, 0, 0);
                }
            }
            #pragma unroll
            for (int nt = 0; nt < 4; ++nt) {
                float v = 0.f;
                #pragma unroll
                for (int mt = 0; mt < 4; ++mt)
                    #pragma unroll
                    for (int r = 0; r < 4; ++r)
                        v = fmaf(part[mt][r], sigmoidf_(acc[mt][nt][r]), v);
                v += __shfl_xor(v, 16, 64);
                v += __shfl_xor(v, 32, 64);
                if (g == 0)
                    res[(size_t)b * 2048 + h * NL + ch * 64 + nt * 16 + c] = (f16)v;
            }
        }
    }
}

// ---------------------------------------------------------------------------
// out GEMM: out[b][0:256] = sigmoid(res[b] @ O)  (f16 MFMA, K=2048)
// ---------------------------------------------------------------------------
__global__ __launch_bounds__(256) void out_gemm(
        const float* __restrict__ x,
        const f16*   __restrict__ res,
        const f16*   __restrict__ OT,
        float* __restrict__ out) {
    int mblk = blockIdx.x >> 1;
    int nblk = blockIdx.x & 1;
    int b0 = mblk * 64;
    int t  = threadIdx.x;
    int w    = t >> 6;
    int lane = t & 63;
    int c = lane & 15;
    int g = lane >> 4;

    __shared__ f16 Ao[64 * APAD];

    f32x4 acc[4][2];
    #pragma unroll
    for (int mt = 0; mt < 4; ++mt)
        #pragma unroll
        for (int nt = 0; nt < 2; ++nt) acc[mt][nt] = (f32x4){0.f, 0.f, 0.f, 0.f};

    for (int chunk = 0; chunk < 8; ++chunk) {
        int kbase = chunk * 256;
        __syncthreads();
        #pragma unroll
        for (int it = 0; it < 8; ++it) {
            int id  = it * 256 + t;
            int row = id >> 5;
            int kc  = (id & 31) << 3;
            *(f16x8*)(&Ao[row * APAD + kc]) =
                *(const f16x8*)(res + (size_t)(b0 + row) * 2048 + kbase + kc);
        }
        __syncthreads();
        #pragma unroll
        for (int kk = 0; kk < 8; ++kk) {
            int k0 = kk * 32 + g * 8;
            f16x8 af[4];
            #pragma unroll
            for (int mt = 0; mt < 4; ++mt)
                af[mt] = *(const f16x8*)(&Ao[(mt * 16 + c) * APAD + k0]);
            #pragma unroll
            for (int nt = 0; nt < 2; ++nt) {
                f16x8 bf = *(const f16x8*)(OT + (size_t)(nblk * 128 + w * 32 + nt * 16 + c) * 2048 + kbase + k0);
                #pragma unroll
                for (int mt = 0; mt < 4; ++mt)
                    acc[mt][nt] = __builtin_amdgcn_mfma_f32_16x16x32_f16(af[mt], bf, acc[mt][nt], 0, 0, 0);
            }
        }
    }
    #pragma unroll
    for (int mt = 0; mt < 4; ++mt)
        #pragma unroll
        for (int nt = 0; nt < 2; ++nt)
            #pragma unroll
            for (int r = 0; r < 4; ++r) {
                int row = mt * 16 + g * 4 + r;
                int col = nblk * 128 + w * 32 + nt * 16 + c;
                out[(size_t)(b0 + row) * 512 + col] = sigmoidf_(acc[mt][nt][r]);
            }
    if (nblk == 1) {                     // origin passthrough for these 64 rows
        for (int r2 = 0; r2 < 64; ++r2)
            out[(size_t)(b0 + r2) * 512 + 256 + t] = x[(size_t)(b0 + r2) * (NSEQ * ND) + t];
    }
}

// ---------------------------------------------------------------------------
extern "C" void kernel_launch(void* const* d_in, const int* in_sizes, int n_in,
                              void* d_out, int out_size, void* d_ws, size_t ws_size,
                              hipStream_t stream) {
    const float* x    = (const float*)d_in[0];
    const float* Wq   = (const float*)d_in[1];
    const float* Wk   = (const float*)d_in[2];
    const float* Wv   = (const float*)d_in[3];
    const float* W    = (const float*)d_in[4];
    const float* O    = (const float*)d_in[5];
    const float* P    = (const float*)d_in[6];
    // d_in[7] = bias: unused — softmax is invariant to the bias*sum(W) shift
    float* out = (float*)d_out;

    // ws carve: wh 3MB | OT 1MB | PKT 512KB | OK 16MB | res 8MB  (~28.5MB)
    char* wsb = (char*)d_ws;
    f16*   wh  = (f16*)wsb;                       // 3*8*256*256 f16 = 3145728 B
    f16*   OT  = (f16*)(wsb + 3145728);           // 256*2048 f16   = 1048576 B
    float* PKT = (float*)(wsb + 4194304);         // 8*256*64 f32   = 524288 B
    float* OK  = (float*)(wsb + 4718592);         // 8*2048*256 f32 = 16777216 B
    f16*   res = (f16*)(wsb + 21495808);          // 2048*2048 f16  = 8388608 B

    wh_kernel<<<384, 256, 0, stream>>>(Wq, Wv, Wk, wh);
    ot_kernel<<<256, 256, 0, stream>>>(O, OT);
    pkt_kernel<<<NH * NS, 256, 0, stream>>>(P, Wk, PKT);
    ok_gemm<<<512, 256, 0, stream>>>(x, wh, OK);
    attn_mfma<<<NB, 256, 0, stream>>>(x, wh, W, PKT, OK, res);
    out_gemm<<<64, 256, 0, stream>>>(x, res, OT, out);
}

// Round 9
// 821.606 us; speedup vs baseline: 1.0517x; 1.0517x over previous
//
#include <hip/hip_runtime.h>
#include <math.h>

#define NB   2048   // batch
#define NSEQ 65     // sequence incl. origin
#define ND   256    // IN_DIM (K)
#define NH   8      // heads
#define NL   256    // L
#define NS   64     // walk length (S-1)
#define APAD 264    // padded A row (aux kernels only)

typedef _Float16 f16;
typedef _Float16 f16x4 __attribute__((ext_vector_type(4)));
typedef _Float16 f16x8 __attribute__((ext_vector_type(8)));
typedef float    f32x4 __attribute__((ext_vector_type(4)));

__device__ __forceinline__ float sigmoidf_(float x) {
    return __builtin_amdgcn_rcpf(1.0f + __expf(-x));
}

// ---------------------------------------------------------------------------
// Prep: Wq/Wv/Wk (H,K,N) f32 -> wh[(h*3+m)][n][k] f16 (k contiguous), m=q,v,k
// ---------------------------------------------------------------------------
__global__ __launch_bounds__(256) void wh_kernel(const float* __restrict__ Wq,
                                                 const float* __restrict__ Wv,
                                                 const float* __restrict__ Wk,
                                                 f16* __restrict__ wh) {
    int hm = blockIdx.x >> 4;            // h*3+m, 24 values
    int h  = hm / 3, m = hm % 3;
    int n  = ((blockIdx.x & 15) << 4) + (threadIdx.x >> 4);
    int kc = (threadIdx.x & 15) << 4;
    const float* src = (m == 0 ? Wq : (m == 1 ? Wv : Wk)) + h * (ND * NL);
    f16x8 t0, t1;
    #pragma unroll
    for (int j = 0; j < 8; ++j) t0[j] = (f16)src[(kc + j) * NL + n];
    #pragma unroll
    for (int j = 0; j < 8; ++j) t1[j] = (f16)src[(kc + 8 + j) * NL + n];
    f16* dst = wh + ((size_t)(hm * 256 + n)) * 256 + kc;
    *(f16x8*)dst       = t0;
    *(f16x8*)(dst + 8) = t1;
}

// ---------------------------------------------------------------------------
// Prep: O (2048,256) f32 -> OT[n][k] f16 (k contiguous)
// ---------------------------------------------------------------------------
__global__ __launch_bounds__(256) void ot_kernel(const float* __restrict__ O,
                                                 f16* __restrict__ OT) {
    int n = blockIdx.x;
    int t = threadIdx.x;
    f16x8 v;
    #pragma unroll
    for (int j = 0; j < 8; ++j) v[j] = (f16)O[(size_t)(t * 8 + j) * 256 + n];
    *(f16x8*)(OT + (size_t)n * 2048 + t * 8) = v;
}

// ---------------------------------------------------------------------------
// PKT[h][l][s] = P[s]·Wk[h][:,l]  (transposed: epilogue reads float4 over s)
// ---------------------------------------------------------------------------
__global__ __launch_bounds__(256) void pkt_kernel(const float* __restrict__ P,
                                                  const float* __restrict__ Wk,
                                                  float* __restrict__ PKT) {
    int h = blockIdx.x >> 6;
    int s = blockIdx.x & 63;
    int t = threadIdx.x;
    __shared__ float p_s[ND];
    p_s[t] = P[s * ND + t];
    __syncthreads();
    const float* wk = Wk + h * (ND * NL) + t;
    float acc = 0.f;
    #pragma unroll 8
    for (int d = 0; d < ND; ++d) acc = fmaf(p_s[d], wk[d * NL], acc);
    PKT[((size_t)h * NL + t) * NS + s] = acc;
}

// ---------------------------------------------------------------------------
// OK[h][b][l] = origin_b · Wk[h][:,l]  as f16 MFMA GEMM
// ---------------------------------------------------------------------------
__global__ __launch_bounds__(256) void ok_gemm(const float* __restrict__ x,
                                               const f16*   __restrict__ wh,
                                               float* __restrict__ OK) {
    int mblk = blockIdx.x >> 4;          // 32
    int nblk = blockIdx.x & 15;          // 16
    int b0 = mblk * 64;
    int h  = nblk >> 1;
    int l0 = (nblk & 1) * 128;
    int t = threadIdx.x;
    int w = t >> 6, lane = t & 63, c = lane & 15, g = lane >> 4;

    __shared__ f16 Ao[64 * APAD];
    #pragma unroll
    for (int it = 0; it < 16; ++it) {
        int idx4 = it * 256 + t;
        int s = idx4 >> 6, kq = idx4 & 63;
        float4 v = *(const float4*)(x + (size_t)(b0 + s) * (NSEQ * ND) + kq * 4);
        *(f16x4*)(&Ao[s * APAD + kq * 4]) = (f16x4){(f16)v.x, (f16)v.y, (f16)v.z, (f16)v.w};
    }
    __syncthreads();

    f32x4 acc[4][2];
    #pragma unroll
    for (int mt = 0; mt < 4; ++mt)
        #pragma unroll
        for (int nt = 0; nt < 2; ++nt) acc[mt][nt] = (f32x4){0.f, 0.f, 0.f, 0.f};

    const f16* bb = wh + ((size_t)((h * 3 + 2) * 256 + l0 + w * 32 + c)) * 256;
    #pragma unroll 2
    for (int kk = 0; kk < 8; ++kk) {
        int k0 = kk * 32 + g * 8;
        f16x8 af[4];
        #pragma unroll
        for (int mt = 0; mt < 4; ++mt)
            af[mt] = *(const f16x8*)(&Ao[(mt * 16 + c) * APAD + k0]);
        #pragma unroll
        for (int nt = 0; nt < 2; ++nt) {
            f16x8 bf = *(const f16x8*)(bb + nt * 16 * 256 + k0);
            #pragma unroll
            for (int mt = 0; mt < 4; ++mt)
                acc[mt][nt] = __builtin_amdgcn_mfma_f32_16x16x32_f16(af[mt], bf, acc[mt][nt], 0, 0, 0);
        }
    }
    #pragma unroll
    for (int mt = 0; mt < 4; ++mt)
        #pragma unroll
        for (int nt = 0; nt < 2; ++nt)
            #pragma unroll
            for (int r = 0; r < 4; ++r)
                OK[((size_t)h * NB + b0 + mt * 16 + g * 4 + r) * NL + l0 + w * 32 + nt * 16 + c]
                    = acc[mt][nt][r];
}

// ---------------------------------------------------------------------------
// Main fused kernel: one block/batch; wave-private heads; 32-col chunks for
// 4 waves/SIMD; chunk+head order ROTATED by blockIdx to break the phase-lock
// between co-resident blocks (part accumulation is order-independent).
// A tile stored XOR-swizzled (k ^= (row&7)<<3): conflict-free ds_read_b128.
// ---------------------------------------------------------------------------
__global__ __launch_bounds__(256, 4) void attn_mfma(
        const float* __restrict__ x,
        const f16*   __restrict__ wh,
        const float* __restrict__ W,
        const float* __restrict__ PKT,
        const float* __restrict__ OK,
        f16* __restrict__ res) {
    int b = blockIdx.x;
    int t = threadIdx.x;
    int w    = t >> 6;
    int lane = t & 63;
    int c = lane & 15;
    int g = lane >> 4;

    __shared__ f16 A[NS * 256];          // 32768 B, swizzled layout

    const float* xb = x + (size_t)b * (NSEQ * ND);

    // --- stage A (walk) once, swizzled ------------------------------------
    #pragma unroll
    for (int it = 0; it < 16; ++it) {
        int idx4 = it * 256 + t;
        int s  = idx4 >> 6;
        int kq = idx4 & 63;
        float4 v = *(const float4*)(xb + (1 + s) * ND + kq * 4);
        int kp = (kq * 4) ^ ((s & 7) << 3);
        *(f16x4*)(&A[s * 256 + kp]) = (f16x4){(f16)v.x, (f16)v.y, (f16)v.z, (f16)v.w};
    }
    __syncthreads();

    int swz = (c & 7) << 3;              // read-side swizzle (row&7 == c&7)
    int rot = b & 7;                     // chunk-phase rotation
    int hrot = (b >> 3) & 1;             // head-phase rotation

    #pragma unroll
    for (int hh = 0; hh < 2; ++hh) {
        int h = w * 2 + ((hh + hrot) & 1);

        // ---- pass 1: q-GEMM + edge, 8 chunks of 32 l-cols ----------------
        float part[4][4];                // [mt][r] -> s = mt*16 + g*4 + r
        #pragma unroll
        for (int mt = 0; mt < 4; ++mt)
            #pragma unroll
            for (int r = 0; r < 4; ++r) part[mt][r] = 0.f;

        for (int ci = 0; ci < 8; ++ci) {
            int ch = (ci + rot) & 7;
            f32x4 acc[4][2];
            #pragma unroll
            for (int mt = 0; mt < 4; ++mt)
                #pragma unroll
                for (int nt = 0; nt < 2; ++nt) acc[mt][nt] = (f32x4){0.f, 0.f, 0.f, 0.f};

            const f16* bq = wh + ((size_t)((h * 3 + 0) * 256 + ch * 32 + c)) * 256;
            #pragma unroll 2
            for (int kk = 0; kk < 8; ++kk) {
                int k0 = kk * 32 + g * 8;
                f16x8 af[4];
                #pragma unroll
                for (int mt = 0; mt < 4; ++mt)
                    af[mt] = *(const f16x8*)(&A[(mt * 16 + c) * 256 + (k0 ^ swz)]);
                #pragma unroll
                for (int nt = 0; nt < 2; ++nt) {
                    f16x8 bf = *(const f16x8*)(bq + nt * 16 * 256 + k0);
                    #pragma unroll
                    for (int mt = 0; mt < 4; ++mt)
                        acc[mt][nt] = __builtin_amdgcn_mfma_f32_16x16x32_f16(af[mt], bf, acc[mt][nt], 0, 0, 0);
                }
            }
            // edge for this chunk (bias omitted: softmax-invariant shift)
            #pragma unroll
            for (int nt = 0; nt < 2; ++nt) {
                int l = ch * 32 + nt * 16 + c;
                float wl  = W[h * NL + l];
                float okv = OK[((size_t)h * NB + b) * NL + l];
                const float* pkcol = PKT + ((size_t)h * NL + l) * NS + g * 4;
                #pragma unroll
                for (int mt = 0; mt < 4; ++mt) {
                    float4 pk4 = *(const float4*)(pkcol + mt * 16);
                    float pks[4] = {pk4.x, pk4.y, pk4.z, pk4.w};
                    #pragma unroll
                    for (int r = 0; r < 4; ++r) {
                        float qs = sigmoidf_(acc[mt][nt][r]);
                        float ks = sigmoidf_(okv + pks[r]);
                        part[mt][r] = fmaf(__cosf(ks * qs), wl, part[mt][r]);
                    }
                }
            }
        }

        // ---- in-wave score reduction over c, then softmax over 64 s ------
        #pragma unroll
        for (int mt = 0; mt < 4; ++mt)
            #pragma unroll
            for (int r = 0; r < 4; ++r) {
                float v = part[mt][r];
                v += __shfl_xor(v, 1, 64);
                v += __shfl_xor(v, 2, 64);
                v += __shfl_xor(v, 4, 64);
                v += __shfl_xor(v, 8, 64);
                part[mt][r] = v;         // score[s], uniform over c
            }
        float m = part[0][0];
        #pragma unroll
        for (int mt = 0; mt < 4; ++mt)
            #pragma unroll
            for (int r = 0; r < 4; ++r) m = fmaxf(m, part[mt][r]);
        m = fmaxf(m, __shfl_xor(m, 16, 64));
        m = fmaxf(m, __shfl_xor(m, 32, 64));
        float ssum = 0.f;
        #pragma unroll
        for (int mt = 0; mt < 4; ++mt)
            #pragma unroll
            for (int r = 0; r < 4; ++r) {
                float e = __expf(part[mt][r] - m);
                part[mt][r] = e;
                ssum += e;
            }
        ssum += __shfl_xor(ssum, 16, 64);
        ssum += __shfl_xor(ssum, 32, 64);
        float rinv = __builtin_amdgcn_rcpf(ssum);
        #pragma unroll
        for (int mt = 0; mt < 4; ++mt)
            #pragma unroll
            for (int r = 0; r < 4; ++r) part[mt][r] *= rinv;   // p_s

        // ---- pass 2: v-GEMM + weighted sigmoid sum, 8 chunks -------------
        for (int ci = 0; ci < 8; ++ci) {
            int ch = (ci + rot) & 7;
            f32x4 acc[4][2];
            #pragma unroll
            for (int mt = 0; mt < 4; ++mt)
                #pragma unroll
                for (int nt = 0; nt < 2; ++nt) acc[mt][nt] = (f32x4){0.f, 0.f, 0.f, 0.f};

            const f16* bv = wh + ((size_t)((h * 3 + 1) * 256 + ch * 32 + c)) * 256;
            #pragma unroll 2
            for (int kk = 0; kk < 8; ++kk) {
                int k0 = kk * 32 + g * 8;
                f16x8 af[4];
                #pragma unroll
                for (int mt = 0; mt < 4; ++mt)
                    af[mt] = *(const f16x8*)(&A[(mt * 16 + c) * 256 + (k0 ^ swz)]);
                #pragma unroll
                for (int nt = 0; nt < 2; ++nt) {
                    f16x8 bf = *(const f16x8*)(bv + nt * 16 * 256 + k0);
                    #pragma unroll
                    for (int mt = 0; mt < 4; ++mt)
                        acc[mt][nt] = __builtin_amdgcn_mfma_f32_16x16x32_f16(af[mt], bf, acc[mt][nt], 0, 0, 0);
                }
            }
            #pragma unroll
            for (int nt = 0; nt < 2; ++nt) {
                float v = 0.f;
                #pragma unroll
                for (int mt = 0; mt < 4; ++mt)
                    #pragma unroll
                    for (int r = 0; r < 4; ++r)
                        v = fmaf(part[mt][r], sigmoidf_(acc[mt][nt][r]), v);
                v += __shfl_xor(v, 16, 64);
                v += __shfl_xor(v, 32, 64);
                if (g == 0)
                    res[(size_t)b * 2048 + h * NL + ch * 32 + nt * 16 + c] = (f16)v;
            }
        }
    }
}

// ---------------------------------------------------------------------------
// out GEMM: out[b][0:256] = sigmoid(res[b] @ O)  (f16 MFMA, K=2048)
// ---------------------------------------------------------------------------
__global__ __launch_bounds__(256) void out_gemm(
        const float* __restrict__ x,
        const f16*   __restrict__ res,
        const f16*   __restrict__ OT,
        float* __restrict__ out) {
    int mblk = blockIdx.x >> 1;
    int nblk = blockIdx.x & 1;
    int b0 = mblk * 64;
    int t  = threadIdx.x;
    int w    = t >> 6;
    int lane = t & 63;
    int c = lane & 15;
    int g = lane >> 4;

    __shared__ f16 Ao[64 * APAD];

    f32x4 acc[4][2];
    #pragma unroll
    for (int mt = 0; mt < 4; ++mt)
        #pragma unroll
        for (int nt = 0; nt < 2; ++nt) acc[mt][nt] = (f32x4){0.f, 0.f, 0.f, 0.f};

    for (int chunk = 0; chunk < 8; ++chunk) {
        int kbase = chunk * 256;
        __syncthreads();
        #pragma unroll
        for (int it = 0; it < 8; ++it) {
            int id  = it * 256 + t;
            int row = id >> 5;
            int kc  = (id & 31) << 3;
            *(f16x8*)(&Ao[row * APAD + kc]) =
                *(const f16x8*)(res + (size_t)(b0 + row) * 2048 + kbase + kc);
        }
        __syncthreads();
        #pragma unroll
        for (int kk = 0; kk < 8; ++kk) {
            int k0 = kk * 32 + g * 8;
            f16x8 af[4];
            #pragma unroll
            for (int mt = 0; mt < 4; ++mt)
                af[mt] = *(const f16x8*)(&Ao[(mt * 16 + c) * APAD + k0]);
            #pragma unroll
            for (int nt = 0; nt < 2; ++nt) {
                f16x8 bf = *(const f16x8*)(OT + (size_t)(nblk * 128 + w * 32 + nt * 16 + c) * 2048 + kbase + k0);
                #pragma unroll
                for (int mt = 0; mt < 4; ++mt)
                    acc[mt][nt] = __builtin_amdgcn_mfma_f32_16x16x32_f16(af[mt], bf, acc[mt][nt], 0, 0, 0);
            }
        }
    }
    #pragma unroll
    for (int mt = 0; mt < 4; ++mt)
        #pragma unroll
        for (int nt = 0; nt < 2; ++nt)
            #pragma unroll
            for (int r = 0; r < 4; ++r) {
                int row = mt * 16 + g * 4 + r;
                int col = nblk * 128 + w * 32 + nt * 16 + c;
                out[(size_t)(b0 + row) * 512 + col] = sigmoidf_(acc[mt][nt][r]);
            }
    if (nblk == 1) {                     // origin passthrough for these 64 rows
        for (int r2 = 0; r2 < 64; ++r2)
            out[(size_t)(b0 + r2) * 512 + 256 + t] = x[(size_t)(b0 + r2) * (NSEQ * ND) + t];
    }
}

// ---------------------------------------------------------------------------
extern "C" void kernel_launch(void* const* d_in, const int* in_sizes, int n_in,
                              void* d_out, int out_size, void* d_ws, size_t ws_size,
                              hipStream_t stream) {
    const float* x    = (const float*)d_in[0];
    const float* Wq   = (const float*)d_in[1];
    const float* Wk   = (const float*)d_in[2];
    const float* Wv   = (const float*)d_in[3];
    const float* W    = (const float*)d_in[4];
    const float* O    = (const float*)d_in[5];
    const float* P    = (const float*)d_in[6];
    // d_in[7] = bias: unused — softmax is invariant to the bias*sum(W) shift
    float* out = (float*)d_out;

    // ws carve: wh 3MB | OT 1MB | PKT 512KB | OK 16MB | res 8MB  (~28.5MB)
    char* wsb = (char*)d_ws;
    f16*   wh  = (f16*)wsb;                       // 3*8*256*256 f16 = 3145728 B
    f16*   OT  = (f16*)(wsb + 3145728);           // 256*2048 f16   = 1048576 B
    float* PKT = (float*)(wsb + 4194304);         // 8*256*64 f32   = 524288 B
    float* OK  = (float*)(wsb + 4718592);         // 8*2048*256 f32 = 16777216 B
    f16*   res = (f16*)(wsb + 21495808);          // 2048*2048 f16  = 8388608 B

    wh_kernel<<<384, 256, 0, stream>>>(Wq, Wv, Wk, wh);
    ot_kernel<<<256, 256, 0, stream>>>(O, OT);
    pkt_kernel<<<NH * NS, 256, 0, stream>>>(P, Wk, PKT);
    ok_gemm<<<512, 256, 0, stream>>>(x, wh, OK);
    attn_mfma<<<NB, 256, 0, stream>>>(x, wh, W, PKT, OK, res);
    out_gemm<<<64, 256, 0, stream>>>(x, res, OT, out);
}